// Round 3
// baseline (289.764 us; speedup 1.0000x reference)
//
#include <hip/hip_runtime.h>

static constexpr int NN  = 100000;   // nodes
static constexpr int NE  = 1600000;  // edges
static constexpr int NG  = 1000;     // graphs
static constexpr int D   = 64;       // D_IN = D_HID
static constexpr int DH  = 32;       // head hidden
static constexpr int DO  = 8;        // out dim
static constexpr int BKT = 128;      // nodes per bucket (7 bits)
static constexpr int NBK = (NN + BKT - 1) / BKT;     // 782
static constexpr int CAP = 2560;     // fixed bucket capacity (mean 2048, 11 sigma)
static constexpr int CHUNK = 4096;                   // edges per chunk block
static constexpr int NCH = (NE + CHUNK - 1) / CHUNK; // 391
static constexpr int MAXW = 13504;   // >= sum_g ceil(cnt_g/8) <= 12500+1000
static constexpr int MAPS = MAXW * 8;                // 108032 slots
static constexpr int NBAND = ((NN - 1) >> 9) + 1;    // 196 src bands (512 nodes each)

typedef __attribute__((ext_vector_type(8))) short bf16x8;
typedef __attribute__((ext_vector_type(4))) float f32x4;

// ---- bf16 helpers (bit-level; values here are never NaN/inf) ----
__device__ __forceinline__ float b2f(unsigned short u) {
    return __uint_as_float(((unsigned int)u) << 16);
}
__device__ __forceinline__ unsigned short f2b(float f) {   // round-to-nearest-even
    unsigned int u = __float_as_uint(f);
    u += 0x7FFFu + ((u >> 16) & 1u);
    return (unsigned short)(u >> 16);
}
__device__ __forceinline__ uint4 pack8(const unsigned short* h) {
    uint4 u;
    u.x = (unsigned)h[0] | ((unsigned)h[1] << 16);
    u.y = (unsigned)h[2] | ((unsigned)h[3] << 16);
    u.z = (unsigned)h[4] | ((unsigned)h[5] << 16);
    u.w = (unsigned)h[6] | ((unsigned)h[7] << 16);
    return u;
}

// block 0: zero bucket cursors; blocks 1,2: split W1/W2 into transposed bf16
// hi/lo; block 3: graph boundaries + padded-wave scan + full wave-map fill.
__global__ __launch_bounds__(1024) void
k_prepw(const float* __restrict__ W1, const float* __restrict__ W2,
        const int* __restrict__ batch,
        unsigned short* __restrict__ wtbuf, int* __restrict__ gcur,
        int* __restrict__ lbg, int* __restrict__ wbase, int* __restrict__ map) {
    __shared__ int bnd[NG + 1];
    __shared__ int wb[NG + 1];
    __shared__ int tsum[256];
    int t = threadIdx.x;
    int b = blockIdx.x;
    if (b == 0) {
        for (int i = t; i < NBK; i += 1024) gcur[i] = 0;
    } else if (b == 3) {
        // graph boundaries: binary searches
        for (int g = t; g <= NG; g += 1024) {
            int lo = 0, hi = NN;
            while (lo < hi) { int m = (lo + hi) >> 1; if (batch[m] < g) lo = m + 1; else hi = m; }
            bnd[g] = lo;
        }
        __syncthreads();
        // prefix scan of per-graph padded wave counts (4 graphs / thread)
        int s = 0, loc[4];
        if (t < 256) {
#pragma unroll
            for (int j = 0; j < 4; ++j) {
                int g = t * 4 + j;
                int pw = (g < NG) ? ((bnd[g + 1] - bnd[g] + 7) >> 3) : 0;
                loc[j] = s; s += pw;
            }
            tsum[t] = s;
        }
        __syncthreads();
        for (int o = 1; o < 256; o <<= 1) {
            int a = (t < 256 && t >= o) ? tsum[t - o] : 0;
            __syncthreads();
            if (t < 256) tsum[t] += a;
            __syncthreads();
        }
        if (t < 256) {
            int base = (t > 0) ? tsum[t - 1] : 0;
#pragma unroll
            for (int j = 0; j < 4; ++j) {
                int g = t * 4 + j;
                if (g < NG) wb[g] = base + loc[j];
            }
            if (t == 255) wb[NG] = tsum[255];
        }
        __syncthreads();
        for (int g = t; g <= NG; g += 1024) { wbase[g] = wb[g]; lbg[g] = bnd[g]; }
        int tot = wb[NG] * 8;
        // fill map[0..tot): coalesced; graph found by binary search on wb
        for (int sI = t; sI < tot; sI += 1024) {
            int w8 = sI >> 3;
            int lo = 0, hi = NG - 1;
            while (lo < hi) { int m = (lo + hi + 1) >> 1; if (wb[m] <= w8) lo = m; else hi = m - 1; }
            int g = lo;
            int i = sI - wb[g] * 8;
            int n = bnd[g + 1] - bnd[g];
            map[sI] = (i < n) ? (bnd[g] + i) : -1;
        }
        for (int sI = tot + t; sI < MAPS; sI += 1024) map[sI] = -1;
    } else {   // b == 1 or 2: weight split
        if (t < 256) {
            const float* W = (b == 2) ? W2 : W1;
            unsigned short* WtHi = wtbuf + (size_t)(b - 1) * 8192;
            unsigned short* WtLo = WtHi + 4096;
            int n = t >> 2, k0 = (t & 3) * 16;
            unsigned short hi[16], lo[16];
#pragma unroll
            for (int i = 0; i < 16; ++i) {
                float v = W[(k0 + i) * 64 + n];
                hi[i] = f2b(v);
                lo[i] = f2b(v - b2f(hi[i]));
            }
            ((uint4*)WtHi)[n * 8 + (t & 3) * 2]     = pack8(hi);
            ((uint4*)WtHi)[n * 8 + (t & 3) * 2 + 1] = pack8(hi + 8);
            ((uint4*)WtLo)[n * 8 + (t & 3) * 2]     = pack8(lo);
            ((uint4*)WtLo)[n * 8 + (t & 3) * 2 + 1] = pack8(lo + 8);
        }
    }
}

// fixed-capacity binning: LDS per-chunk count -> one global atomic per
// (block,bucket) reserves a range inside bucket b's [b*CAP, b*CAP+CAP) slab.
// packed edge = src*128 + (dst & 127).
__global__ __launch_bounds__(512) void
k_bin(const int* __restrict__ src, const int* __restrict__ dst,
      int* __restrict__ gcur, int* __restrict__ ebuf) {
    __shared__ int lcnt[NBK];
    __shared__ int lbase[NBK];
    int t = threadIdx.x;
    long base = (long)blockIdx.x * CHUNK;
    for (int b = t; b < NBK; b += 512) lcnt[b] = 0;
    __syncthreads();
    int pk[8], bk[8], of[8];
#pragma unroll
    for (int j = 0; j < 8; ++j) {
        long i = base + j * 512 + t;
        if (i < NE) {
            int d = dst[i];
            bk[j] = d >> 7;
            pk[j] = src[i] * BKT + (d & (BKT - 1));
            of[j] = atomicAdd(&lcnt[bk[j]], 1);
        } else bk[j] = -1;
    }
    __syncthreads();
    for (int b = t; b < NBK; b += 512) {
        int c = lcnt[b];
        if (c) lbase[b] = b * CAP + atomicAdd(&gcur[b], c);
    }
    __syncthreads();
#pragma unroll
    for (int j = 0; j < 8; ++j)
        if (bk[j] >= 0) ebuf[lbase[bk[j]] + of[j]] = pk[j];
}

// per-bucket: LDS histogram of local idx -> rowptr/deg/dinv, then LDS
// counting-sort of the bucket's edges by src band (src>>9) and chunk-ordered
// CSR scatter -> each node's adjacency list is src-sorted (~512 granularity).
// Sorted lists make all concurrent agg waves sweep ascending src together,
// so the active gather band fits per-XCD L2.
__global__ __launch_bounds__(512) void
k_csrdeg(const int* __restrict__ gcur, const int* __restrict__ ebuf,
         int* __restrict__ rowptr, int* __restrict__ deg, float* __restrict__ dinv,
         int* __restrict__ csr) {
    __shared__ int earr[CAP];        // raw edges
    __shared__ int esrt[CAP];        // band-sorted edges
    __shared__ int hist[BKT];
    __shared__ int sc[BKT];
    __shared__ int lcur[BKT];
    __shared__ int bh[NBAND];
    __shared__ int bs[NBAND];
    int b = blockIdx.x, t = threadIdx.x;
    if (t < BKT) hist[t] = 0;
    for (int i = t; i < NBAND; i += 512) bh[i] = 0;
    __syncthreads();
    int beg = b * CAP;
    int cnt = gcur[b];
    for (int e = t; e < cnt; e += 512) {
        int p = ebuf[beg + e];
        earr[e] = p;
        atomicAdd(&hist[p & (BKT - 1)], 1);
        atomicAdd(&bh[p >> 16], 1);        // band = src>>9 = p>>16
    }
    __syncthreads();
    if (t < BKT) sc[t] = hist[t];
    if (t < NBAND) bs[t] = bh[t];
    __syncthreads();
    for (int o = 1; o < 256; o <<= 1) {    // joint scan: dst-hist (128) + bands (196)
        int a1 = (t < BKT && t >= o) ? sc[t - o] : 0;
        int a2 = (t < NBAND && t >= o) ? bs[t - o] : 0;
        __syncthreads();
        if (t < BKT) sc[t] += a1;
        if (t < NBAND) bs[t] += a2;
        __syncthreads();
    }
    if (t < NBAND) bh[t] = bs[t] - bh[t];  // exclusive band cursor
    int v0 = b * BKT;
    if (t < BKT) {
        int v = v0 + t;
        if (v < NN) {
            int excl = beg + sc[t] - hist[t];
            rowptr[v] = excl;
            deg[v]    = hist[t];
            dinv[v]   = rsqrtf((float)(hist[t] + 1));
            lcur[t]   = excl;
        }
    }
    __syncthreads();
    for (int e = t; e < cnt; e += 512) {   // counting-sort into esrt
        int p = earr[e];
        int pos = atomicAdd(&bh[p >> 16], 1);
        esrt[pos] = p;
    }
    __syncthreads();
    for (int base2 = 0; base2 < cnt; base2 += 512) {  // chunk-ordered scatter
        int e = base2 + t;
        int p = (e < cnt) ? esrt[e] : -1;
        if (p >= 0) {
            int slot = atomicAdd(&lcur[p & (BKT - 1)], 1);
            csr[slot] = p >> 7;
        }
        __syncthreads();
    }
}

// MFMA matmul: out[n][:] = bf16(dinv[n] * (A[n][:] @ W)), 64 nodes/block.
// Split-bf16: A@W = Ahi·Whi + Ahi·Wlo + Alo·Whi — ~f32 accurate (f32 A input).
__global__ __launch_bounds__(256) void
k_mm_mfma(const float* __restrict__ Ain, const unsigned short* __restrict__ wt,
          const float* __restrict__ dinv, uint4* __restrict__ out) {
    __shared__ unsigned short smem[4 * 64 * 72];   // 36864 B
    unsigned short* Ahi  = smem;
    unsigned short* Alo  = smem + 4608;
    unsigned short* WtHi = smem + 9216;
    unsigned short* WtLo = smem + 13824;
    int t = threadIdx.x;
    int r = t >> 2, cc = t & 3, c0 = cc * 16;
    long n0 = (long)blockIdx.x * 64;
    {   // stage Wt (hi/lo), coalesced
        const uint4* H = (const uint4*)wt;
        const uint4* L = (const uint4*)(wt + 4096);
        uint4* dh = (uint4*)&WtHi[r * 72 + c0];
        uint4* dl = (uint4*)&WtLo[r * 72 + c0];
        dh[0] = H[r * 8 + cc * 2]; dh[1] = H[r * 8 + cc * 2 + 1];
        dl[0] = L[r * 8 + cc * 2]; dl[1] = L[r * 8 + cc * 2 + 1];
    }
    {   // stage A (convert + split)
        long n = n0 + r; if (n >= NN) n = NN - 1;
        const float4* X = (const float4*)Ain;
        unsigned short hi[16], lo[16];
#pragma unroll
        for (int i = 0; i < 4; ++i) {
            float4 v = X[n * 16 + cc * 4 + i];
            float vv[4] = {v.x, v.y, v.z, v.w};
#pragma unroll
            for (int j = 0; j < 4; ++j) {
                unsigned short h = f2b(vv[j]);
                hi[i * 4 + j] = h;
                lo[i * 4 + j] = f2b(vv[j] - b2f(h));
            }
        }
        uint4* dh = (uint4*)&Ahi[r * 72 + c0];
        uint4* dl = (uint4*)&Alo[r * 72 + c0];
        dh[0] = pack8(hi); dh[1] = pack8(hi + 8);
        dl[0] = pack8(lo); dl[1] = pack8(lo + 8);
    }
    __syncthreads();
    int lane = t & 63, w = t >> 6;
    int q = lane >> 4, m = lane & 15;
    f32x4 acc[4] = {{0.f,0.f,0.f,0.f},{0.f,0.f,0.f,0.f},{0.f,0.f,0.f,0.f},{0.f,0.f,0.f,0.f}};
#pragma unroll
    for (int s = 0; s < 2; ++s) {
        int ko = s * 32 + q * 8;
        bf16x8 ah = *(const bf16x8*)&Ahi[(w * 16 + m) * 72 + ko];
        bf16x8 al = *(const bf16x8*)&Alo[(w * 16 + m) * 72 + ko];
#pragma unroll
        for (int c = 0; c < 4; ++c) {
            bf16x8 bh = *(const bf16x8*)&WtHi[(c * 16 + m) * 72 + ko];
            bf16x8 bl = *(const bf16x8*)&WtLo[(c * 16 + m) * 72 + ko];
            acc[c] = __builtin_amdgcn_mfma_f32_16x16x32_bf16(ah, bh, acc[c], 0, 0, 0);
            acc[c] = __builtin_amdgcn_mfma_f32_16x16x32_bf16(ah, bl, acc[c], 0, 0, 0);
            acc[c] = __builtin_amdgcn_mfma_f32_16x16x32_bf16(al, bh, acc[c], 0, 0, 0);
        }
    }
    __syncthreads();
    float* Ct = (float*)smem;   // 64 x 68 f32 tile (overlaps dead A/Wt)
#pragma unroll
    for (int c = 0; c < 4; ++c)
#pragma unroll
        for (int rr = 0; rr < 4; ++rr)
            Ct[(w * 16 + q * 4 + rr) * 68 + c * 16 + m] = acc[c][rr];
    __syncthreads();
    {
        long n = n0 + r;
        if (n < NN) {
            float dv = dinv[n];
            unsigned short ob[16];
#pragma unroll
            for (int i = 0; i < 4; ++i) {
                float4 v = *(const float4*)&Ct[r * 68 + c0 + i * 4];
                ob[i * 4 + 0] = f2b(v.x * dv); ob[i * 4 + 1] = f2b(v.y * dv);
                ob[i * 4 + 2] = f2b(v.z * dv); ob[i * 4 + 3] = f2b(v.w * dv);
            }
            out[n * 8 + cc * 2]     = pack8(ob);
            out[n * 8 + cc * 2 + 1] = pack8(ob + 8);
        }
    }
}

// Fused agg(layer1, relu) -> LDS h1 tile -> MFMA @ W2 -> g2.  64 nodes/block,
// natural order (coalesced csr/self reads, coalesced writes).
__global__ __launch_bounds__(512) void
k_aggmm(const int* __restrict__ rowptr, const int* __restrict__ deg,
        const int* __restrict__ csr,
        const uint4* __restrict__ g4, const float* __restrict__ dinv,
        const float* __restrict__ bias, const unsigned short* __restrict__ wt,
        uint4* __restrict__ out) {
    __shared__ unsigned short smem[3 * 4608];   // Ahi | WtHi | WtLo (27648 B)
    unsigned short* Ahi  = smem;
    unsigned short* WtHi = smem + 4608;
    unsigned short* WtLo = smem + 9216;
    int t = threadIdx.x;
    long n0 = (long)blockIdx.x * 64;
    if (t < 256) {   // stage W2 (hi/lo)
        int r = t >> 2, cc = t & 3, c0 = cc * 16;
        const uint4* H = (const uint4*)wt;
        const uint4* L = (const uint4*)(wt + 4096);
        uint4* dh = (uint4*)&WtHi[r * 72 + c0];
        uint4* dl = (uint4*)&WtLo[r * 72 + c0];
        dh[0] = H[r * 8 + cc * 2]; dh[1] = H[r * 8 + cc * 2 + 1];
        dl[0] = L[r * 8 + cc * 2]; dl[1] = L[r * 8 + cc * 2 + 1];
    }
    // phase 1: aggregate 8 waves x 8 nodes
    int lane = t & 63, w = t >> 6;
    int fg = lane & 7, slot = lane >> 3;
    int ln = w * 8 + slot;                 // local node 0..63
    long v = n0 + ln;
    int vc = (v < NN) ? (int)v : NN - 1;
    int beg = rowptr[vc];
    int len = (v < NN) ? deg[vc] : 0;
    int lmax = len;
    lmax = max(lmax, __shfl_xor(lmax, 8));
    lmax = max(lmax, __shfl_xor(lmax, 16));
    lmax = max(lmax, __shfl_xor(lmax, 32));
    float acc[8];
    {
        uint4 sv = g4[(long)vc * 8 + fg];
        if (v >= NN) { sv.x = sv.y = sv.z = sv.w = 0u; }
        acc[0] = __uint_as_float(sv.x << 16); acc[1] = __uint_as_float(sv.x & 0xFFFF0000u);
        acc[2] = __uint_as_float(sv.y << 16); acc[3] = __uint_as_float(sv.y & 0xFFFF0000u);
        acc[4] = __uint_as_float(sv.z << 16); acc[5] = __uint_as_float(sv.z & 0xFFFF0000u);
        acc[6] = __uint_as_float(sv.w << 16); acc[7] = __uint_as_float(sv.w & 0xFFFF0000u);
    }
    for (int e = 0; e < lmax; e += 8) {
#pragma unroll
        for (int j = 0; j < 8; ++j) {
            int ee = e + j;
            float m = (ee < len) ? 1.f : 0.f;
            int idx = beg + ((ee < len) ? ee : 0);
            int srcn = csr[idx];
            uint4 a = g4[(long)srcn * 8 + fg];
            acc[0] += m * __uint_as_float(a.x << 16);
            acc[1] += m * __uint_as_float(a.x & 0xFFFF0000u);
            acc[2] += m * __uint_as_float(a.y << 16);
            acc[3] += m * __uint_as_float(a.y & 0xFFFF0000u);
            acc[4] += m * __uint_as_float(a.z << 16);
            acc[5] += m * __uint_as_float(a.z & 0xFFFF0000u);
            acc[6] += m * __uint_as_float(a.w << 16);
            acc[7] += m * __uint_as_float(a.w & 0xFFFF0000u);
        }
    }
    {
        float dv = dinv[vc];
        unsigned short ob[8];
#pragma unroll
        for (int k = 0; k < 8; ++k) {
            float x = fmaxf(acc[k] * dv + bias[fg * 8 + k], 0.f);   // h1 = relu(..)
            ob[k] = f2b(x);
        }
        *(uint4*)&Ahi[ln * 72 + fg * 8] = pack8(ob);
    }
    __syncthreads();
    // phase 2: MFMA h1 @ W2 (8 waves: row strip = (w&3)*16, 2 col-blocks each)
    int q = lane >> 4, m = lane & 15;
    int rs = (w & 3) * 16;
    int cb0 = (w >> 2) * 2;
    f32x4 c2[2] = {{0.f,0.f,0.f,0.f},{0.f,0.f,0.f,0.f}};
#pragma unroll
    for (int s = 0; s < 2; ++s) {
        int ko = s * 32 + q * 8;
        bf16x8 ah = *(const bf16x8*)&Ahi[(rs + m) * 72 + ko];
#pragma unroll
        for (int c = 0; c < 2; ++c) {
            bf16x8 bh = *(const bf16x8*)&WtHi[((cb0 + c) * 16 + m) * 72 + ko];
            bf16x8 bl = *(const bf16x8*)&WtLo[((cb0 + c) * 16 + m) * 72 + ko];
            c2[c] = __builtin_amdgcn_mfma_f32_16x16x32_bf16(ah, bh, c2[c], 0, 0, 0);
            c2[c] = __builtin_amdgcn_mfma_f32_16x16x32_bf16(ah, bl, c2[c], 0, 0, 0);
        }
    }
    __syncthreads();
    float* Ct = (float*)smem;   // 64 x 68 f32 = 17408 B (overlaps dead A/Wt)
#pragma unroll
    for (int c = 0; c < 2; ++c)
#pragma unroll
        for (int rr = 0; rr < 4; ++rr)
            Ct[(rs + q * 4 + rr) * 68 + (cb0 + c) * 16 + m] = c2[c][rr];
    __syncthreads();
    {
        int r = t >> 3, c8 = (t & 7) * 8;
        long n = n0 + r;
        if (n < NN) {
            float dv = dinv[n];
            float4 a = *(const float4*)&Ct[r * 68 + c8];
            float4 b = *(const float4*)&Ct[r * 68 + c8 + 4];
            unsigned short ob[8] = {f2b(a.x * dv), f2b(a.y * dv), f2b(a.z * dv), f2b(a.w * dv),
                                    f2b(b.x * dv), f2b(b.y * dv), f2b(b.z * dv), f2b(b.w * dv)};
            out[n * 8 + (t & 7)] = pack8(ob);
        }
    }
}

// Fused layer-2 aggregation + pool partial: wave w handles map[w*8..w*8+8)
// (single-graph by construction, natural order within graph).  Wave-reduce
// over the 8 nodes -> one coalesced 256 B partial row per wave.  No atomics.
__global__ __launch_bounds__(256) void
k_agg2pool(const int* __restrict__ rowptr, const int* __restrict__ deg,
           const int* __restrict__ csr,
           const uint4* __restrict__ g4, const float* __restrict__ dinv,
           const int* __restrict__ map, float* __restrict__ partial) {
    int t = threadIdx.x;
    int lane = t & 63;
    int fg = lane & 7;
    int slot = lane >> 3;
    int w = blockIdx.x * 4 + (t >> 6);   // global wave id, MAXW/4 blocks
    int v = map[w * 8 + slot];           // -1 = pad slot
    int vc = (v < 0) ? 0 : v;
    int beg = rowptr[vc];
    int len = (v < 0) ? 0 : deg[vc];
    int lmax = len;
    lmax = max(lmax, __shfl_xor(lmax, 8));
    lmax = max(lmax, __shfl_xor(lmax, 16));
    lmax = max(lmax, __shfl_xor(lmax, 32));
    float acc[8];
    {
        uint4 sv = g4[(long)vc * 8 + fg];
        if (v < 0) { sv.x = sv.y = sv.z = sv.w = 0u; }
        acc[0] = __uint_as_float(sv.x << 16); acc[1] = __uint_as_float(sv.x & 0xFFFF0000u);
        acc[2] = __uint_as_float(sv.y << 16); acc[3] = __uint_as_float(sv.y & 0xFFFF0000u);
        acc[4] = __uint_as_float(sv.z << 16); acc[5] = __uint_as_float(sv.z & 0xFFFF0000u);
        acc[6] = __uint_as_float(sv.w << 16); acc[7] = __uint_as_float(sv.w & 0xFFFF0000u);
    }
    for (int e = 0; e < lmax; e += 8) {
#pragma unroll
        for (int j = 0; j < 8; ++j) {
            int ee = e + j;
            float m = (ee < len) ? 1.f : 0.f;
            int idx2 = beg + ((ee < len) ? ee : 0);
            int srcn = csr[idx2];
            uint4 a = g4[(long)srcn * 8 + fg];
            acc[0] += m * __uint_as_float(a.x << 16);
            acc[1] += m * __uint_as_float(a.x & 0xFFFF0000u);
            acc[2] += m * __uint_as_float(a.y << 16);
            acc[3] += m * __uint_as_float(a.y & 0xFFFF0000u);
            acc[4] += m * __uint_as_float(a.z << 16);
            acc[5] += m * __uint_as_float(a.z & 0xFFFF0000u);
            acc[6] += m * __uint_as_float(a.w << 16);
            acc[7] += m * __uint_as_float(a.w & 0xFFFF0000u);
        }
    }
    float dv = dinv[vc];
#pragma unroll
    for (int k = 0; k < 8; ++k) {
        acc[k] *= dv;                       // h2 (sans b2; b2 folded into head)
        acc[k] += __shfl_xor(acc[k], 8);    // reduce over the wave's 8 nodes
        acc[k] += __shfl_xor(acc[k], 16);
        acc[k] += __shfl_xor(acc[k], 32);
    }
    if (slot == 0) {   // lanes 0..7 write the 256 B partial row, coalesced
        float4* p4 = (float4*)&partial[(long)w * 64];
        f32x4 a = {acc[0], acc[1], acc[2], acc[3]};
        f32x4 b = {acc[4], acc[5], acc[6], acc[7]};
        p4[fg * 2]     = *(float4*)&a;
        p4[fg * 2 + 1] = *(float4*)&b;
    }
}

// head: sum graph g's partial rows (contiguous, coalesced), mean + b2, MLP.
__global__ void k_head(const float* __restrict__ partial,
                       const int* __restrict__ lbg, const int* __restrict__ wbase,
                       const float* __restrict__ b2,
                       const float* __restrict__ lw1, const float* __restrict__ lb1,
                       const float* __restrict__ lw2, const float* __restrict__ lb2,
                       float* __restrict__ out) {
    __shared__ float pl[D];
    __shared__ float z[DH];
    int g = blockIdx.x;
    int t = threadIdx.x;  // 64, lane = dim
    int w0 = wbase[g], w1 = wbase[g + 1];
    int cnt = lbg[g + 1] - lbg[g];
    float s = 0.f;
    for (int w = w0; w < w1; ++w) s += partial[(long)w * 64 + t];
    pl[t] = (cnt > 0) ? (s / (float)cnt + b2[t]) : 0.f;
    __syncthreads();
    if (t < DH) {
        float a = lb1[t];
#pragma unroll
        for (int k = 0; k < D; ++k) a += pl[k] * lw1[k * DH + t];
        z[t] = fmaxf(a, 0.f);
    }
    __syncthreads();
    if (t < DO) {
        float a = lb2[t];
#pragma unroll
        for (int j = 0; j < DH; ++j) a += z[j] * lw2[j * DO + t];
        out[g * DO + t] = a;
    }
}

extern "C" void kernel_launch(void* const* d_in, const int* in_sizes, int n_in,
                              void* d_out, int out_size, void* d_ws, size_t ws_size,
                              hipStream_t stream) {
    const float* x    = (const float*)d_in[0];
    const int*   ei   = (const int*)  d_in[1];
    const int*   batch= (const int*)  d_in[2];
    const float* W1   = (const float*)d_in[3];
    const float* b1   = (const float*)d_in[4];
    const float* W2   = (const float*)d_in[5];
    const float* b2   = (const float*)d_in[6];
    const float* lw1  = (const float*)d_in[7];
    const float* lb1  = (const float*)d_in[8];
    const float* lw2  = (const float*)d_in[9];
    const float* lb2  = (const float*)d_in[10];
    float* out = (float*)d_out;

    const int* srcv = ei;        // edge_index[0]
    const int* dstv = ei + NE;   // edge_index[1]

    char* ws = (char*)d_ws;
    size_t off = 0;
    auto alloc = [&](size_t bytes) {
        void* p = ws + off;
        off = (off + bytes + 255) & ~(size_t)255;
        return p;
    };
    int*   gcur   = (int*)  alloc((size_t)NBK * 4);
    int*   rowptr = (int*)  alloc((size_t)NN * 4);
    int*   deg    = (int*)  alloc((size_t)NN * 4);
    int*   csr    = (int*)  alloc((size_t)NBK * CAP * 4);  // 8.0 MB slabbed
    float* dinv   = (float*)alloc((size_t)NN * 4);
    int*   lbg    = (int*)  alloc((size_t)(NG + 1) * 4);
    int*   wbase  = (int*)  alloc((size_t)(NG + 1) * 4);
    int*   map    = (int*)  alloc((size_t)MAPS * 4);       // 432 KB
    float* partial= (float*)alloc((size_t)MAXW * D * 4);   // 3.46 MB
    unsigned short* wtbuf = (unsigned short*)alloc((size_t)4 * 4096 * 2);  // 32 KB
    unsigned short* bufA = (unsigned short*)alloc((size_t)NN * D * 2);    // 12.8 MB
    unsigned short* bufB = (unsigned short*)alloc((size_t)NN * D * 2);    // 12.8 MB
    int*   ebuf   = (int*)bufA;  // binning scratch (8.0 MB); dead before bufA written

    k_prepw  <<<4, 1024, 0, stream>>>(W1, W2, batch, wtbuf, gcur, lbg, wbase, map);
    k_bin    <<<NCH, 512, 0, stream>>>(srcv, dstv, gcur, ebuf);
    k_csrdeg <<<NBK, 512, 0, stream>>>(gcur, ebuf, rowptr, deg, dinv, csr);

    const int MMB = (NN + 63) / 64;   // 1563

    // layer 1 mm: g1 = bf16((x @ W1) * dinv) -> bufA
    k_mm_mfma<<<MMB, 256, 0, stream>>>(x, wtbuf, dinv, (uint4*)bufA);
    // fused: h1 = relu(agg(g1)) (LDS tile) ; g2 = bf16((h1 @ W2) * dinv) -> bufB
    k_aggmm<<<MMB, 512, 0, stream>>>(rowptr, deg, csr, (const uint4*)bufA, dinv, b1,
                                     wtbuf + 8192, (uint4*)bufB);
    // layer 2 agg fused with pool partials (no h2 round-trip, no atomics)
    k_agg2pool<<<MAXW / 4, 256, 0, stream>>>(rowptr, deg, csr, (const uint4*)bufB, dinv,
                                             map, partial);
    k_head<<<NG, 64, 0, stream>>>(partial, lbg, wbase, b2, lw1, lb1, lw2, lb2, out);
}

// Round 4
// 211.414 us; speedup vs baseline: 1.3706x; 1.3706x over previous
//
#include <hip/hip_runtime.h>

static constexpr int NN  = 100000;   // nodes
static constexpr int NE  = 1600000;  // edges
static constexpr int NG  = 1000;     // graphs
static constexpr int D   = 64;       // D_IN = D_HID
static constexpr int DH  = 32;       // head hidden
static constexpr int DO  = 8;        // out dim
static constexpr int BKT = 128;      // nodes per bucket (7 bits)
static constexpr int NBK = (NN + BKT - 1) / BKT;     // 782
static constexpr int CAP = 2560;     // fixed bucket capacity (mean 2048, 11 sigma)
static constexpr int CHUNK = 4096;                   // edges per chunk block
static constexpr int NCH = (NE + CHUNK - 1) / CHUNK; // 391
static constexpr int MAXW = 13504;   // >= sum_g ceil(cnt_g/8) <= 12500+1000
static constexpr int MAPS = MAXW * 8;                // 108032 slots
static constexpr int NBAND = ((NN - 1) >> 9) + 1;    // 196 src bands (512 nodes each)

typedef __attribute__((ext_vector_type(8))) short bf16x8;
typedef __attribute__((ext_vector_type(4))) float f32x4;

// ---- bf16 helpers (bit-level; values here are never NaN/inf) ----
__device__ __forceinline__ float b2f(unsigned short u) {
    return __uint_as_float(((unsigned int)u) << 16);
}
__device__ __forceinline__ unsigned short f2b(float f) {   // round-to-nearest-even
    unsigned int u = __float_as_uint(f);
    u += 0x7FFFu + ((u >> 16) & 1u);
    return (unsigned short)(u >> 16);
}
__device__ __forceinline__ uint4 pack8(const unsigned short* h) {
    uint4 u;
    u.x = (unsigned)h[0] | ((unsigned)h[1] << 16);
    u.y = (unsigned)h[2] | ((unsigned)h[3] << 16);
    u.z = (unsigned)h[4] | ((unsigned)h[5] << 16);
    u.w = (unsigned)h[6] | ((unsigned)h[7] << 16);
    return u;
}

// block 0: zero bucket cursors; blocks 1,2: split W1/W2 into transposed bf16
// hi/lo; block 3: graph boundaries + padded-wave prefix scan (wbase/lbg);
// blocks 4..11: memset wave map to -1.  (Map FILL stays in k_fillmap: doing it
// here single-block was a 96 µs serialization — round-3 lesson.)
__global__ __launch_bounds__(1024) void
k_prepw(const float* __restrict__ W1, const float* __restrict__ W2,
        const int* __restrict__ batch,
        unsigned short* __restrict__ wtbuf, int* __restrict__ gcur,
        int* __restrict__ lbg, int* __restrict__ wbase, int* __restrict__ map) {
    __shared__ int bnd[NG + 1];
    __shared__ int tsum[256];
    int t = threadIdx.x;
    int b = blockIdx.x;
    if (b == 0) {
        for (int i = t; i < NBK; i += 1024) gcur[i] = 0;
    } else if (b == 3) {
        // graph boundaries: one binary search per thread
        for (int g = t; g <= NG; g += 1024) {
            int lo = 0, hi = NN;
            while (lo < hi) { int m = (lo + hi) >> 1; if (batch[m] < g) lo = m + 1; else hi = m; }
            bnd[g] = lo;
        }
        __syncthreads();
        // prefix scan of per-graph padded wave counts (4 graphs / thread)
        int s = 0, loc[4];
        if (t < 256) {
#pragma unroll
            for (int j = 0; j < 4; ++j) {
                int g = t * 4 + j;
                int pw = (g < NG) ? ((bnd[g + 1] - bnd[g] + 7) >> 3) : 0;
                loc[j] = s; s += pw;
            }
            tsum[t] = s;
        }
        __syncthreads();
        for (int o = 1; o < 256; o <<= 1) {
            int a = (t < 256 && t >= o) ? tsum[t - o] : 0;
            __syncthreads();
            if (t < 256) tsum[t] += a;
            __syncthreads();
        }
        if (t < 256) {
            int base = (t > 0) ? tsum[t - 1] : 0;
#pragma unroll
            for (int j = 0; j < 4; ++j) {
                int g = t * 4 + j;
                if (g < NG) wbase[g] = base + loc[j];
            }
            if (t == 255) wbase[NG] = tsum[255];
        }
        if (t <= NG) lbg[t] = bnd[t];
    } else if (b >= 4) {
        int4 m4 = {-1, -1, -1, -1};
        for (int i = (b - 4) * 1024 + t; i < MAPS / 4; i += 8 * 1024)
            ((int4*)map)[i] = m4;
    } else {   // b == 1 or 2: weight split
        if (t < 256) {
            const float* W = (b == 2) ? W2 : W1;
            unsigned short* WtHi = wtbuf + (size_t)(b - 1) * 8192;
            unsigned short* WtLo = WtHi + 4096;
            int n = t >> 2, k0 = (t & 3) * 16;
            unsigned short hi[16], lo[16];
#pragma unroll
            for (int i = 0; i < 16; ++i) {
                float v = W[(k0 + i) * 64 + n];
                hi[i] = f2b(v);
                lo[i] = f2b(v - b2f(hi[i]));
            }
            ((uint4*)WtHi)[n * 8 + (t & 3) * 2]     = pack8(hi);
            ((uint4*)WtHi)[n * 8 + (t & 3) * 2 + 1] = pack8(hi + 8);
            ((uint4*)WtLo)[n * 8 + (t & 3) * 2]     = pack8(lo);
            ((uint4*)WtLo)[n * 8 + (t & 3) * 2 + 1] = pack8(lo + 8);
        }
    }
}

// per-graph wave map: graph g's nodes (natural order) at slots
// [wbase[g]*8, wbase[g]*8 + ceil(cnt/8)*8), -1 pads.  Every 8-slot wave is
// single-graph by construction -> pooling needs no atomics at all.
__global__ __launch_bounds__(128) void
k_fillmap(const int* __restrict__ lbg, const int* __restrict__ wbase,
          int* __restrict__ map) {
    int g = blockIdx.x;
    int base = wbase[g] * 8;
    int lb = lbg[g], n = lbg[g + 1] - lb;
    int padded = (n + 7) & ~7;
    for (int i = threadIdx.x; i < padded; i += 128)
        map[base + i] = (i < n) ? (lb + i) : -1;
}

// fixed-capacity binning: LDS per-chunk count -> one global atomic per
// (block,bucket) reserves a range inside bucket b's [b*CAP, b*CAP+CAP) slab.
// packed edge = src*128 + (dst & 127).
__global__ __launch_bounds__(512) void
k_bin(const int* __restrict__ src, const int* __restrict__ dst,
      int* __restrict__ gcur, int* __restrict__ ebuf) {
    __shared__ int lcnt[NBK];
    __shared__ int lbase[NBK];
    int t = threadIdx.x;
    long base = (long)blockIdx.x * CHUNK;
    for (int b = t; b < NBK; b += 512) lcnt[b] = 0;
    __syncthreads();
    int pk[8], bk[8], of[8];
#pragma unroll
    for (int j = 0; j < 8; ++j) {
        long i = base + j * 512 + t;
        if (i < NE) {
            int d = dst[i];
            bk[j] = d >> 7;
            pk[j] = src[i] * BKT + (d & (BKT - 1));
            of[j] = atomicAdd(&lcnt[bk[j]], 1);
        } else bk[j] = -1;
    }
    __syncthreads();
    for (int b = t; b < NBK; b += 512) {
        int c = lcnt[b];
        if (c) lbase[b] = b * CAP + atomicAdd(&gcur[b], c);
    }
    __syncthreads();
#pragma unroll
    for (int j = 0; j < 8; ++j)
        if (bk[j] >= 0) ebuf[lbase[bk[j]] + of[j]] = pk[j];
}

// per-bucket: LDS histogram of local idx -> rowptr/deg/dinv, then LDS
// counting-sort of the bucket's edges by src band (src>>9) and chunk-ordered
// CSR scatter -> each node's adjacency list is src-sorted (~512 granularity).
// Sorted lists make all concurrent agg waves sweep ascending src together,
// so the active gather band fits per-XCD L2.
__global__ __launch_bounds__(512) void
k_csrdeg(const int* __restrict__ gcur, const int* __restrict__ ebuf,
         int* __restrict__ rowptr, int* __restrict__ deg, float* __restrict__ dinv,
         int* __restrict__ csr) {
    __shared__ int earr[CAP];        // raw edges
    __shared__ int esrt[CAP];        // band-sorted edges
    __shared__ int hist[BKT];
    __shared__ int sc[BKT];
    __shared__ int lcur[BKT];
    __shared__ int bh[NBAND];
    __shared__ int bs[NBAND];
    int b = blockIdx.x, t = threadIdx.x;
    if (t < BKT) hist[t] = 0;
    for (int i = t; i < NBAND; i += 512) bh[i] = 0;
    __syncthreads();
    int beg = b * CAP;
    int cnt = gcur[b];
    for (int e = t; e < cnt; e += 512) {
        int p = ebuf[beg + e];
        earr[e] = p;
        atomicAdd(&hist[p & (BKT - 1)], 1);
        atomicAdd(&bh[p >> 16], 1);        // band = src>>9 = p>>16
    }
    __syncthreads();
    if (t < BKT) sc[t] = hist[t];
    if (t < NBAND) bs[t] = bh[t];
    __syncthreads();
    for (int o = 1; o < 256; o <<= 1) {    // joint scan: dst-hist (128) + bands (196)
        int a1 = (t < BKT && t >= o) ? sc[t - o] : 0;
        int a2 = (t < NBAND && t >= o) ? bs[t - o] : 0;
        __syncthreads();
        if (t < BKT) sc[t] += a1;
        if (t < NBAND) bs[t] += a2;
        __syncthreads();
    }
    if (t < NBAND) bh[t] = bs[t] - bh[t];  // exclusive band cursor
    int v0 = b * BKT;
    if (t < BKT) {
        int v = v0 + t;
        if (v < NN) {
            int excl = beg + sc[t] - hist[t];
            rowptr[v] = excl;
            deg[v]    = hist[t];
            dinv[v]   = rsqrtf((float)(hist[t] + 1));
            lcur[t]   = excl;
        }
    }
    __syncthreads();
    for (int e = t; e < cnt; e += 512) {   // counting-sort into esrt
        int p = earr[e];
        int pos = atomicAdd(&bh[p >> 16], 1);
        esrt[pos] = p;
    }
    __syncthreads();
    for (int base2 = 0; base2 < cnt; base2 += 512) {  // chunk-ordered scatter
        int e = base2 + t;
        int p = (e < cnt) ? esrt[e] : -1;
        if (p >= 0) {
            int slot = atomicAdd(&lcur[p & (BKT - 1)], 1);
            csr[slot] = p >> 7;
        }
        __syncthreads();
    }
}

// MFMA matmul: out[n][:] = bf16(dinv[n] * (A[n][:] @ W)), 64 nodes/block.
// Split-bf16: A@W = Ahi·Whi + Ahi·Wlo + Alo·Whi — ~f32 accurate (f32 A input).
__global__ __launch_bounds__(256) void
k_mm_mfma(const float* __restrict__ Ain, const unsigned short* __restrict__ wt,
          const float* __restrict__ dinv, uint4* __restrict__ out) {
    __shared__ unsigned short smem[4 * 64 * 72];   // 36864 B
    unsigned short* Ahi  = smem;
    unsigned short* Alo  = smem + 4608;
    unsigned short* WtHi = smem + 9216;
    unsigned short* WtLo = smem + 13824;
    int t = threadIdx.x;
    int r = t >> 2, cc = t & 3, c0 = cc * 16;
    long n0 = (long)blockIdx.x * 64;
    {   // stage Wt (hi/lo), coalesced
        const uint4* H = (const uint4*)wt;
        const uint4* L = (const uint4*)(wt + 4096);
        uint4* dh = (uint4*)&WtHi[r * 72 + c0];
        uint4* dl = (uint4*)&WtLo[r * 72 + c0];
        dh[0] = H[r * 8 + cc * 2]; dh[1] = H[r * 8 + cc * 2 + 1];
        dl[0] = L[r * 8 + cc * 2]; dl[1] = L[r * 8 + cc * 2 + 1];
    }
    {   // stage A (convert + split)
        long n = n0 + r; if (n >= NN) n = NN - 1;
        const float4* X = (const float4*)Ain;
        unsigned short hi[16], lo[16];
#pragma unroll
        for (int i = 0; i < 4; ++i) {
            float4 v = X[n * 16 + cc * 4 + i];
            float vv[4] = {v.x, v.y, v.z, v.w};
#pragma unroll
            for (int j = 0; j < 4; ++j) {
                unsigned short h = f2b(vv[j]);
                hi[i * 4 + j] = h;
                lo[i * 4 + j] = f2b(vv[j] - b2f(h));
            }
        }
        uint4* dh = (uint4*)&Ahi[r * 72 + c0];
        uint4* dl = (uint4*)&Alo[r * 72 + c0];
        dh[0] = pack8(hi); dh[1] = pack8(hi + 8);
        dl[0] = pack8(lo); dl[1] = pack8(lo + 8);
    }
    __syncthreads();
    int lane = t & 63, w = t >> 6;
    int q = lane >> 4, m = lane & 15;
    f32x4 acc[4] = {{0.f,0.f,0.f,0.f},{0.f,0.f,0.f,0.f},{0.f,0.f,0.f,0.f},{0.f,0.f,0.f,0.f}};
#pragma unroll
    for (int s = 0; s < 2; ++s) {
        int ko = s * 32 + q * 8;
        bf16x8 ah = *(const bf16x8*)&Ahi[(w * 16 + m) * 72 + ko];
        bf16x8 al = *(const bf16x8*)&Alo[(w * 16 + m) * 72 + ko];
#pragma unroll
        for (int c = 0; c < 4; ++c) {
            bf16x8 bh = *(const bf16x8*)&WtHi[(c * 16 + m) * 72 + ko];
            bf16x8 bl = *(const bf16x8*)&WtLo[(c * 16 + m) * 72 + ko];
            acc[c] = __builtin_amdgcn_mfma_f32_16x16x32_bf16(ah, bh, acc[c], 0, 0, 0);
            acc[c] = __builtin_amdgcn_mfma_f32_16x16x32_bf16(ah, bl, acc[c], 0, 0, 0);
            acc[c] = __builtin_amdgcn_mfma_f32_16x16x32_bf16(al, bh, acc[c], 0, 0, 0);
        }
    }
    __syncthreads();
    float* Ct = (float*)smem;   // 64 x 68 f32 tile (overlaps dead A/Wt)
#pragma unroll
    for (int c = 0; c < 4; ++c)
#pragma unroll
        for (int rr = 0; rr < 4; ++rr)
            Ct[(w * 16 + q * 4 + rr) * 68 + c * 16 + m] = acc[c][rr];
    __syncthreads();
    {
        long n = n0 + r;
        if (n < NN) {
            float dv = dinv[n];
            unsigned short ob[16];
#pragma unroll
            for (int i = 0; i < 4; ++i) {
                float4 v = *(const float4*)&Ct[r * 68 + c0 + i * 4];
                ob[i * 4 + 0] = f2b(v.x * dv); ob[i * 4 + 1] = f2b(v.y * dv);
                ob[i * 4 + 2] = f2b(v.z * dv); ob[i * 4 + 3] = f2b(v.w * dv);
            }
            out[n * 8 + cc * 2]     = pack8(ob);
            out[n * 8 + cc * 2 + 1] = pack8(ob + 8);
        }
    }
}

// Fused agg(layer1, relu) -> LDS h1 tile -> MFMA @ W2 -> g2.  64 nodes/block,
// natural order (coalesced csr/self reads, coalesced writes).
__global__ __launch_bounds__(512) void
k_aggmm(const int* __restrict__ rowptr, const int* __restrict__ deg,
        const int* __restrict__ csr,
        const uint4* __restrict__ g4, const float* __restrict__ dinv,
        const float* __restrict__ bias, const unsigned short* __restrict__ wt,
        uint4* __restrict__ out) {
    __shared__ unsigned short smem[3 * 4608];   // Ahi | WtHi | WtLo (27648 B)
    unsigned short* Ahi  = smem;
    unsigned short* WtHi = smem + 4608;
    unsigned short* WtLo = smem + 9216;
    int t = threadIdx.x;
    long n0 = (long)blockIdx.x * 64;
    if (t < 256) {   // stage W2 (hi/lo)
        int r = t >> 2, cc = t & 3, c0 = cc * 16;
        const uint4* H = (const uint4*)wt;
        const uint4* L = (const uint4*)(wt + 4096);
        uint4* dh = (uint4*)&WtHi[r * 72 + c0];
        uint4* dl = (uint4*)&WtLo[r * 72 + c0];
        dh[0] = H[r * 8 + cc * 2]; dh[1] = H[r * 8 + cc * 2 + 1];
        dl[0] = L[r * 8 + cc * 2]; dl[1] = L[r * 8 + cc * 2 + 1];
    }
    // phase 1: aggregate 8 waves x 8 nodes
    int lane = t & 63, w = t >> 6;
    int fg = lane & 7, slot = lane >> 3;
    int ln = w * 8 + slot;                 // local node 0..63
    long v = n0 + ln;
    int vc = (v < NN) ? (int)v : NN - 1;
    int beg = rowptr[vc];
    int len = (v < NN) ? deg[vc] : 0;
    int lmax = len;
    lmax = max(lmax, __shfl_xor(lmax, 8));
    lmax = max(lmax, __shfl_xor(lmax, 16));
    lmax = max(lmax, __shfl_xor(lmax, 32));
    float acc[8];
    {
        uint4 sv = g4[(long)vc * 8 + fg];
        if (v >= NN) { sv.x = sv.y = sv.z = sv.w = 0u; }
        acc[0] = __uint_as_float(sv.x << 16); acc[1] = __uint_as_float(sv.x & 0xFFFF0000u);
        acc[2] = __uint_as_float(sv.y << 16); acc[3] = __uint_as_float(sv.y & 0xFFFF0000u);
        acc[4] = __uint_as_float(sv.z << 16); acc[5] = __uint_as_float(sv.z & 0xFFFF0000u);
        acc[6] = __uint_as_float(sv.w << 16); acc[7] = __uint_as_float(sv.w & 0xFFFF0000u);
    }
    for (int e = 0; e < lmax; e += 8) {
#pragma unroll
        for (int j = 0; j < 8; ++j) {
            int ee = e + j;
            float m = (ee < len) ? 1.f : 0.f;
            int idx = beg + ((ee < len) ? ee : 0);
            int srcn = csr[idx];
            uint4 a = g4[(long)srcn * 8 + fg];
            acc[0] += m * __uint_as_float(a.x << 16);
            acc[1] += m * __uint_as_float(a.x & 0xFFFF0000u);
            acc[2] += m * __uint_as_float(a.y << 16);
            acc[3] += m * __uint_as_float(a.y & 0xFFFF0000u);
            acc[4] += m * __uint_as_float(a.z << 16);
            acc[5] += m * __uint_as_float(a.z & 0xFFFF0000u);
            acc[6] += m * __uint_as_float(a.w << 16);
            acc[7] += m * __uint_as_float(a.w & 0xFFFF0000u);
        }
    }
    {
        float dv = dinv[vc];
        unsigned short ob[8];
#pragma unroll
        for (int k = 0; k < 8; ++k) {
            float x = fmaxf(acc[k] * dv + bias[fg * 8 + k], 0.f);   // h1 = relu(..)
            ob[k] = f2b(x);
        }
        *(uint4*)&Ahi[ln * 72 + fg * 8] = pack8(ob);
    }
    __syncthreads();
    // phase 2: MFMA h1 @ W2 (8 waves: row strip = (w&3)*16, 2 col-blocks each)
    int q = lane >> 4, m = lane & 15;
    int rs = (w & 3) * 16;
    int cb0 = (w >> 2) * 2;
    f32x4 c2[2] = {{0.f,0.f,0.f,0.f},{0.f,0.f,0.f,0.f}};
#pragma unroll
    for (int s = 0; s < 2; ++s) {
        int ko = s * 32 + q * 8;
        bf16x8 ah = *(const bf16x8*)&Ahi[(rs + m) * 72 + ko];
#pragma unroll
        for (int c = 0; c < 2; ++c) {
            bf16x8 bh = *(const bf16x8*)&WtHi[((cb0 + c) * 16 + m) * 72 + ko];
            bf16x8 bl = *(const bf16x8*)&WtLo[((cb0 + c) * 16 + m) * 72 + ko];
            c2[c] = __builtin_amdgcn_mfma_f32_16x16x32_bf16(ah, bh, c2[c], 0, 0, 0);
            c2[c] = __builtin_amdgcn_mfma_f32_16x16x32_bf16(ah, bl, c2[c], 0, 0, 0);
        }
    }
    __syncthreads();
    float* Ct = (float*)smem;   // 64 x 68 f32 = 17408 B (overlaps dead A/Wt)
#pragma unroll
    for (int c = 0; c < 2; ++c)
#pragma unroll
        for (int rr = 0; rr < 4; ++rr)
            Ct[(rs + q * 4 + rr) * 68 + (cb0 + c) * 16 + m] = c2[c][rr];
    __syncthreads();
    {
        int r = t >> 3, c8 = (t & 7) * 8;
        long n = n0 + r;
        if (n < NN) {
            float dv = dinv[n];
            float4 a = *(const float4*)&Ct[r * 68 + c8];
            float4 b = *(const float4*)&Ct[r * 68 + c8 + 4];
            unsigned short ob[8] = {f2b(a.x * dv), f2b(a.y * dv), f2b(a.z * dv), f2b(a.w * dv),
                                    f2b(b.x * dv), f2b(b.y * dv), f2b(b.z * dv), f2b(b.w * dv)};
            out[n * 8 + (t & 7)] = pack8(ob);
        }
    }
}

// Fused layer-2 aggregation + pool partial: wave w handles map[w*8..w*8+8)
// (single-graph by construction, natural order within graph).  Wave-reduce
// over the 8 nodes -> one coalesced 256 B partial row per wave.  No atomics.
__global__ __launch_bounds__(256) void
k_agg2pool(const int* __restrict__ rowptr, const int* __restrict__ deg,
           const int* __restrict__ csr,
           const uint4* __restrict__ g4, const float* __restrict__ dinv,
           const int* __restrict__ map, float* __restrict__ partial) {
    int t = threadIdx.x;
    int lane = t & 63;
    int fg = lane & 7;
    int slot = lane >> 3;
    int w = blockIdx.x * 4 + (t >> 6);   // global wave id, MAXW/4 blocks
    int v = map[w * 8 + slot];           // -1 = pad slot
    int vc = (v < 0) ? 0 : v;
    int beg = rowptr[vc];
    int len = (v < 0) ? 0 : deg[vc];
    int lmax = len;
    lmax = max(lmax, __shfl_xor(lmax, 8));
    lmax = max(lmax, __shfl_xor(lmax, 16));
    lmax = max(lmax, __shfl_xor(lmax, 32));
    float acc[8];
    {
        uint4 sv = g4[(long)vc * 8 + fg];
        if (v < 0) { sv.x = sv.y = sv.z = sv.w = 0u; }
        acc[0] = __uint_as_float(sv.x << 16); acc[1] = __uint_as_float(sv.x & 0xFFFF0000u);
        acc[2] = __uint_as_float(sv.y << 16); acc[3] = __uint_as_float(sv.y & 0xFFFF0000u);
        acc[4] = __uint_as_float(sv.z << 16); acc[5] = __uint_as_float(sv.z & 0xFFFF0000u);
        acc[6] = __uint_as_float(sv.w << 16); acc[7] = __uint_as_float(sv.w & 0xFFFF0000u);
    }
    for (int e = 0; e < lmax; e += 8) {
#pragma unroll
        for (int j = 0; j < 8; ++j) {
            int ee = e + j;
            float m = (ee < len) ? 1.f : 0.f;
            int idx2 = beg + ((ee < len) ? ee : 0);
            int srcn = csr[idx2];
            uint4 a = g4[(long)srcn * 8 + fg];
            acc[0] += m * __uint_as_float(a.x << 16);
            acc[1] += m * __uint_as_float(a.x & 0xFFFF0000u);
            acc[2] += m * __uint_as_float(a.y << 16);
            acc[3] += m * __uint_as_float(a.y & 0xFFFF0000u);
            acc[4] += m * __uint_as_float(a.z << 16);
            acc[5] += m * __uint_as_float(a.z & 0xFFFF0000u);
            acc[6] += m * __uint_as_float(a.w << 16);
            acc[7] += m * __uint_as_float(a.w & 0xFFFF0000u);
        }
    }
    float dv = dinv[vc];
#pragma unroll
    for (int k = 0; k < 8; ++k) {
        acc[k] *= dv;                       // h2 (sans b2; b2 folded into head)
        acc[k] += __shfl_xor(acc[k], 8);    // reduce over the wave's 8 nodes
        acc[k] += __shfl_xor(acc[k], 16);
        acc[k] += __shfl_xor(acc[k], 32);
    }
    if (slot == 0) {   // lanes 0..7 write the 256 B partial row, coalesced
        float4* p4 = (float4*)&partial[(long)w * 64];
        f32x4 a = {acc[0], acc[1], acc[2], acc[3]};
        f32x4 b = {acc[4], acc[5], acc[6], acc[7]};
        p4[fg * 2]     = *(float4*)&a;
        p4[fg * 2 + 1] = *(float4*)&b;
    }
}

// head: sum graph g's partial rows (contiguous, coalesced), mean + b2, MLP.
__global__ void k_head(const float* __restrict__ partial,
                       const int* __restrict__ lbg, const int* __restrict__ wbase,
                       const float* __restrict__ b2,
                       const float* __restrict__ lw1, const float* __restrict__ lb1,
                       const float* __restrict__ lw2, const float* __restrict__ lb2,
                       float* __restrict__ out) {
    __shared__ float pl[D];
    __shared__ float z[DH];
    int g = blockIdx.x;
    int t = threadIdx.x;  // 64, lane = dim
    int w0 = wbase[g], w1 = wbase[g + 1];
    int cnt = lbg[g + 1] - lbg[g];
    float s = 0.f;
    for (int w = w0; w < w1; ++w) s += partial[(long)w * 64 + t];
    pl[t] = (cnt > 0) ? (s / (float)cnt + b2[t]) : 0.f;
    __syncthreads();
    if (t < DH) {
        float a = lb1[t];
#pragma unroll
        for (int k = 0; k < D; ++k) a += pl[k] * lw1[k * DH + t];
        z[t] = fmaxf(a, 0.f);
    }
    __syncthreads();
    if (t < DO) {
        float a = lb2[t];
#pragma unroll
        for (int j = 0; j < DH; ++j) a += z[j] * lw2[j * DO + t];
        out[g * DO + t] = a;
    }
}

extern "C" void kernel_launch(void* const* d_in, const int* in_sizes, int n_in,
                              void* d_out, int out_size, void* d_ws, size_t ws_size,
                              hipStream_t stream) {
    const float* x    = (const float*)d_in[0];
    const int*   ei   = (const int*)  d_in[1];
    const int*   batch= (const int*)  d_in[2];
    const float* W1   = (const float*)d_in[3];
    const float* b1   = (const float*)d_in[4];
    const float* W2   = (const float*)d_in[5];
    const float* b2   = (const float*)d_in[6];
    const float* lw1  = (const float*)d_in[7];
    const float* lb1  = (const float*)d_in[8];
    const float* lw2  = (const float*)d_in[9];
    const float* lb2  = (const float*)d_in[10];
    float* out = (float*)d_out;

    const int* srcv = ei;        // edge_index[0]
    const int* dstv = ei + NE;   // edge_index[1]

    char* ws = (char*)d_ws;
    size_t off = 0;
    auto alloc = [&](size_t bytes) {
        void* p = ws + off;
        off = (off + bytes + 255) & ~(size_t)255;
        return p;
    };
    int*   gcur   = (int*)  alloc((size_t)NBK * 4);
    int*   rowptr = (int*)  alloc((size_t)NN * 4);
    int*   deg    = (int*)  alloc((size_t)NN * 4);
    int*   csr    = (int*)  alloc((size_t)NBK * CAP * 4);  // 8.0 MB slabbed
    float* dinv   = (float*)alloc((size_t)NN * 4);
    int*   lbg    = (int*)  alloc((size_t)(NG + 1) * 4);
    int*   wbase  = (int*)  alloc((size_t)(NG + 1) * 4);
    int*   map    = (int*)  alloc((size_t)MAPS * 4);       // 432 KB
    float* partial= (float*)alloc((size_t)MAXW * D * 4);   // 3.46 MB
    unsigned short* wtbuf = (unsigned short*)alloc((size_t)4 * 4096 * 2);  // 32 KB
    unsigned short* bufA = (unsigned short*)alloc((size_t)NN * D * 2);    // 12.8 MB
    unsigned short* bufB = (unsigned short*)alloc((size_t)NN * D * 2);    // 12.8 MB
    int*   ebuf   = (int*)bufA;  // binning scratch (8.0 MB); dead before bufA written

    k_prepw  <<<12, 1024, 0, stream>>>(W1, W2, batch, wtbuf, gcur, lbg, wbase, map);
    k_fillmap<<<NG, 128, 0, stream>>>(lbg, wbase, map);
    k_bin    <<<NCH, 512, 0, stream>>>(srcv, dstv, gcur, ebuf);
    k_csrdeg <<<NBK, 512, 0, stream>>>(gcur, ebuf, rowptr, deg, dinv, csr);

    const int MMB = (NN + 63) / 64;   // 1563

    // layer 1 mm: g1 = bf16((x @ W1) * dinv) -> bufA
    k_mm_mfma<<<MMB, 256, 0, stream>>>(x, wtbuf, dinv, (uint4*)bufA);
    // fused: h1 = relu(agg(g1)) (LDS tile) ; g2 = bf16((h1 @ W2) * dinv) -> bufB
    k_aggmm<<<MMB, 512, 0, stream>>>(rowptr, deg, csr, (const uint4*)bufA, dinv, b1,
                                     wtbuf + 8192, (uint4*)bufB);
    // layer 2 agg fused with pool partials (no h2 round-trip, no atomics)
    k_agg2pool<<<MAXW / 4, 256, 0, stream>>>(rowptr, deg, csr, (const uint4*)bufB, dinv,
                                             map, partial);
    k_head<<<NG, 64, 0, stream>>>(partial, lbg, wbase, b2, lw1, lb1, lw2, lb2, out);
}